// Round 16
// baseline (832.820 us; speedup 1.0000x reference)
//
#include <hip/hip_runtime.h>
#include <hip/hip_bf16.h>
#include <cstdint>

#define N_NODES   100000
#define N_EDGES   1600000
#define N_GRAPHS  128
#define HDIM      256
#define BN_EPS    1e-5f
#define NROWS_PAD 100096       // 782*128
#define NBUCK     782          // ceil(N/128)
#define EPB       8192         // edges per block, bucket passes
#define CAP       3584         // max edges per bucket

typedef _Float16 f16;
typedef __attribute__((ext_vector_type(8))) _Float16 f16x8;
typedef __attribute__((ext_vector_type(4))) float f32x4;

static __device__ __forceinline__ int imin(int a, int b) { return a < b ? a : b; }
static __device__ __forceinline__ int imax(int a, int b) { return a > b ? a : b; }

static __device__ __forceinline__ float h2f(unsigned short s) {
    return (float)__builtin_bit_cast(f16, s);
}
static __device__ __forceinline__ float hlo(unsigned u) { return h2f((unsigned short)(u & 0xffff)); }
static __device__ __forceinline__ float hhi(unsigned u) { return h2f((unsigned short)(u >> 16)); }
static __device__ __forceinline__ unsigned short f2h(float f) {
    return __builtin_bit_cast(unsigned short, (f16)f);
}
static __device__ __forceinline__ unsigned pk2(float a, float b) {
    return (unsigned)f2h(a) | ((unsigned)f2h(b) << 16);
}

static __device__ __forceinline__ void gload_lds16(void* ldsp, const void* gp) {
    __builtin_amdgcn_global_load_lds(
        (const __attribute__((address_space(1))) void*)gp,
        (__attribute__((address_space(3))) void*)ldsp, 16, 0, 0);
}

// ---------------------------------------------------- CSR build (bucketed)
__global__ __launch_bounds__(256) void k_bucket_count(const int* __restrict__ ei,
                                                      int* __restrict__ bcnt, int E) {
    __shared__ int h[NBUCK];
    for (int i = threadIdx.x; i < NBUCK; i += 256) h[i] = 0;
    __syncthreads();
    const int e0 = blockIdx.x * EPB;
    const int e1 = imin(e0 + EPB, E);
    for (int e = e0 + threadIdx.x; e < e1; e += 256)
        atomicAdd(&h[ei[E + e] >> 7], 1);
    __syncthreads();
    for (int i = threadIdx.x; i < NBUCK; i += 256)
        if (h[i]) atomicAdd(&bcnt[i], h[i]);
}

__global__ __launch_bounds__(1024) void k_bucket_scan(const int* __restrict__ bcnt,
                                                      int* __restrict__ bbase,
                                                      int* __restrict__ bcur) {
    __shared__ int sh[1024];
    const int t = threadIdx.x;
    const int v = (t < NBUCK) ? bcnt[t] : 0;
    sh[t] = v;
    __syncthreads();
    for (int off = 1; off < 1024; off <<= 1) {
        int x = (t >= off) ? sh[t - off] : 0;
        __syncthreads();
        sh[t] += x;
        __syncthreads();
    }
    const int excl = sh[t] - v;
    if (t <= NBUCK) bbase[t] = excl;   // bbase[NBUCK] == E
    if (t < NBUCK)  bcur[t]  = excl;
}

__global__ __launch_bounds__(256) void k_bucket_scatter(const int* __restrict__ ei,
                                                        int* __restrict__ bcur,
                                                        unsigned* __restrict__ bpack, int E) {
    __shared__ int h[NBUCK];
    __shared__ int base[NBUCK];
    for (int i = threadIdx.x; i < NBUCK; i += 256) h[i] = 0;
    __syncthreads();
    const int e0 = blockIdx.x * EPB;
    const int e1 = imin(e0 + EPB, E);
    for (int e = e0 + threadIdx.x; e < e1; e += 256)
        atomicAdd(&h[ei[E + e] >> 7], 1);
    __syncthreads();
    for (int i = threadIdx.x; i < NBUCK; i += 256) {
        int c = h[i];
        base[i] = c ? atomicAdd(&bcur[i], c) : 0;
        h[i] = 0;                       // reuse as block-local cursor
    }
    __syncthreads();
    for (int e = e0 + threadIdx.x; e < e1; e += 256) {
        int d = ei[E + e];
        int b = d >> 7;
        int p = base[b] + atomicAdd(&h[b], 1);
        bpack[p] = ((unsigned)(d & 127) << 17) | (unsigned)ei[e];
    }
}

__global__ __launch_bounds__(256) void k_bucket_sort(const unsigned* __restrict__ bpack,
                                                     const int* __restrict__ bbase,
                                                     int* __restrict__ csr_src,
                                                     int* __restrict__ row_ptr, int n) {
    __shared__ unsigned arr[CAP];
    __shared__ int sorted[CAP];
    __shared__ int hist[128], cur[128];
    const int b = blockIdx.x;
    const int t = threadIdx.x;
    const int lo = bbase[b];
    const int m = imin(bbase[b + 1] - lo, CAP);
    if (t < 128) hist[t] = 0;
    __syncthreads();
    for (int j = t; j < m; j += 256) {
        unsigned p = bpack[lo + j];
        arr[j] = p;
        atomicAdd(&hist[p >> 17], 1);
    }
    __syncthreads();
    if (t < 128) cur[t] = hist[t];
    __syncthreads();
    for (int off = 1; off < 128; off <<= 1) {
        int x = 0;
        if (t < 128 && t >= off) x = cur[t - off];
        __syncthreads();
        if (t < 128) cur[t] += x;
        __syncthreads();
    }
    if (t < 128) {
        int excl = cur[t] - hist[t];
        int node = b * 128 + t;
        if (node < n) row_ptr[node] = lo + excl;
        cur[t] = excl;
    }
    if (b == NBUCK - 1 && t == 0) row_ptr[n] = bbase[NBUCK];
    __syncthreads();
    for (int j = t; j < m; j += 256) {
        unsigned p = arr[j];
        int pos = atomicAdd(&cur[p >> 17], 1);
        sorted[pos] = (int)(p & 0x1ffff);
    }
    __syncthreads();
    for (int j = t; j < m; j += 256) csr_src[lo + j] = sorted[j];
}

// ---------------------------------------------------------------- casts/prep
__global__ void k_cast_x(const float* __restrict__ x, unsigned short* __restrict__ xh, int total4) {
    int i = blockIdx.x * blockDim.x + threadIdx.x;
    if (i < total4) {
        float4 v = reinterpret_cast<const float4*>(x)[i];
        uint2 o;
        o.x = pk2(v.x, v.y);
        o.y = pk2(v.z, v.w);
        reinterpret_cast<uint2*>(xh)[i] = o;
    }
}

// all 6 weights in one dispatch: W[K][256] fp32 -> Wt[256][K] f16
struct WArgs {
    const float* w[6];
    unsigned short* wt[6];
    int K[6];
};

__global__ __launch_bounds__(256) void k_prep_w_all(WArgs a) {
    __shared__ float t[32][33];
    const int i = blockIdx.z;
    const int K = a.K[i];
    const int kb = blockIdx.x * 32;
    if (kb >= K) return;
    const int nb = blockIdx.y * 32;
    const float* w = a.w[i];
    unsigned short* wt = a.wt[i];
    int c = threadIdx.x & 31, r0 = threadIdx.x >> 5;
    for (int r = r0; r < 32; r += 8) t[r][c] = w[(size_t)(kb + r) * HDIM + nb + c];
    __syncthreads();
    for (int r = r0; r < 32; r += 8) wt[(size_t)(nb + r) * K + kb + c] = f2h(t[c][r]);
}

// per-graph node counts
__global__ __launch_bounds__(256) void k_gcnt(const int* __restrict__ batch,
                                              int* __restrict__ gcnt, int n) {
    __shared__ int h[N_GRAPHS];
    if (threadIdx.x < N_GRAPHS) h[threadIdx.x] = 0;
    __syncthreads();
    for (int i = blockIdx.x * 256 + threadIdx.x; i < n; i += gridDim.x * 256)
        atomicAdd(&h[batch[i]], 1);
    __syncthreads();
    if (threadIdx.x < N_GRAPHS && h[threadIdx.x])
        atomicAdd(&gcnt[threadIdx.x], h[threadIdx.x]);
}

// ------------------------------------------------------------ aggregation
// z = mean_j h_j + h_i, optionally with previous-layer BN folded:
//   z = sc*(mean + self) + tb*(deg>0 ? 2 : 1)
// 16B/lane gather; EPI edges per wave issue; shfl-xor cross-group reduce.
template <int D>
__global__ __launch_bounds__(256) void k_aggregate_f16(const unsigned short* __restrict__ h,
                                                       const int* __restrict__ row_ptr,
                                                       const int* __restrict__ csr_src,
                                                       const float* __restrict__ st,
                                                       unsigned short* __restrict__ z, int n) {
    int wid = blockIdx.x * 4 + (threadIdx.x >> 6);
    wid = __builtin_amdgcn_readfirstlane(wid);
    if (wid >= n) return;
    const int lane = threadIdx.x & 63;
    constexpr int LG  = D / 8;       // lanes per row (32 for D=256, 16 for D=128)
    constexpr int EPI = 64 / LG;     // edges per issue (2 or 4)
    const int sub = lane / LG;
    const int col = (lane % LG) * 8;
    const unsigned short* hc = h + col;
    const int beg = row_ptr[wid];
    const int end = row_ptr[wid + 1];

    float acc[8];
#pragma unroll
    for (int j = 0; j < 8; ++j) acc[j] = 0.f;

    auto addv = [&](uint4 v) {
        acc[0] += hlo(v.x); acc[1] += hhi(v.x);
        acc[2] += hlo(v.y); acc[3] += hhi(v.y);
        acc[4] += hlo(v.z); acc[5] += hhi(v.z);
        acc[6] += hlo(v.w); acc[7] += hhi(v.w);
    };

    int e = beg;
    for (; e + 8 <= end; e += 8) {
        int s[8 / EPI];
#pragma unroll
        for (int u = 0; u < 8 / EPI; ++u) s[u] = csr_src[e + u * EPI + sub];
#pragma unroll
        for (int u = 0; u < 8 / EPI; ++u)
            addv(*reinterpret_cast<const uint4*>(hc + (size_t)s[u] * D));
    }
    for (; e + EPI <= end; e += EPI) {
        int s = csr_src[e + sub];
        addv(*reinterpret_cast<const uint4*>(hc + (size_t)s * D));
    }
    if (e < end && sub < end - e) {
        int s = csr_src[e + sub];
        addv(*reinterpret_cast<const uint4*>(hc + (size_t)s * D));
    }

#pragma unroll
    for (int j = 0; j < 8; ++j) {
        if (EPI == 4) acc[j] += __shfl_xor(acc[j], 16, 64);
        acc[j] += __shfl_xor(acc[j], 32, 64);
    }

    const float inv = 1.0f / (float)imax(end - beg, 1);
    uint4 sv = *reinterpret_cast<const uint4*>(hc + (size_t)wid * D);
    float m[8];
    m[0] = acc[0] * inv + hlo(sv.x); m[1] = acc[1] * inv + hhi(sv.x);
    m[2] = acc[2] * inv + hlo(sv.y); m[3] = acc[3] * inv + hhi(sv.y);
    m[4] = acc[4] * inv + hlo(sv.z); m[5] = acc[5] * inv + hhi(sv.z);
    m[6] = acc[6] * inv + hlo(sv.w); m[7] = acc[7] * inv + hhi(sv.w);
    if (st) {
        const float tbm = (end > beg) ? 2.f : 1.f;
#pragma unroll
        for (int j = 0; j < 8; ++j) m[j] = st[col + j] * m[j] + tbm * st[HDIM + col + j];
    }
    if (sub == 0) {
        uint4 o;
        o.x = pk2(m[0], m[1]); o.y = pk2(m[2], m[3]);
        o.z = pk2(m[4], m[5]); o.w = pk2(m[6], m[7]);
        *reinterpret_cast<uint4*>(z + (size_t)wid * D + col) = o;
    }
}

// ------------------------------------------------------------------- GEMM
// r14 PROVEN-FAST STRUCTURE (745us total, ~59us/GEMM): BM=128, BN=128
// (grid.y=2), BK=64, 256 threads = 4 waves (2x2), wave 64x64, mfma
// 16x16x32 f16. BOTH A and Wt staged via global_load_lds with wave-uniform
// LDS dest (p*256+wv*64)*16 and XOR-pre-swizzled per-lane global source;
// swizzled ds_read_b128 on consume. Compiler-managed waitcnt/barriers ONLY.
// LESSONS (do not revisit): BN=256 4-wave (r15) -27us; per-lane LDS dest
// (r4/r6/r7) 3x slower; W-direct-from-global (r8/r13) 213us; min-waves=4
// (r5) spills acc.
// STATS: fused BN sum/sumsq. POOL: fused per-graph RAW pooling (BN affine
// applied later in k_head via gcnt). WRITE_C=false skips the C store
// (layer-3 second GEMM: h feeds only stats+pool).
template <int K, bool STATS, bool POOL, bool WRITE_C>
__global__ __launch_bounds__(256, 2) void k_gemm_mfma(const unsigned short* __restrict__ A,
                                                      const unsigned short* __restrict__ Wt,
                                                      const float* __restrict__ bias,
                                                      unsigned short* __restrict__ C,
                                                      float* __restrict__ stats,
                                                      const int* __restrict__ batch,
                                                      float* __restrict__ pooled, int n) {
    __shared__ unsigned char Als[128 * 64 * 2];   // 16 KB
    __shared__ unsigned char Bls[128 * 64 * 2];   // 16 KB
    __shared__ float ssum[128], ssq[128];
    __shared__ float psum[4][128];
    __shared__ int bsh[128];

    const int tid = threadIdx.x;
    const int lane = tid & 63;
    const int wv = tid >> 6;              // 0..3
    const int wm = wv >> 1, wn = wv & 1;  // 2 x 2
    const long row0 = (long)blockIdx.x * 128;
    const int n0 = blockIdx.y * 128;

    if constexpr (STATS) {
        if (tid < 128) { ssum[tid] = 0.f; ssq[tid] = 0.f; }
    }
    if constexpr (POOL) {
        for (int i = tid; i < 4 * 128; i += 256) (&psum[0][0])[i] = 0.f;
        if (tid < 128) bsh[tid] = batch[imin((int)row0 + tid, n - 1)];
    }

    f32x4 acc[4][4];
#pragma unroll
    for (int m = 0; m < 4; ++m)
#pragma unroll
        for (int nn = 0; nn < 4; ++nn) acc[m][nn] = (f32x4){0.f, 0.f, 0.f, 0.f};

    const int srow = tid >> 3;      // 0..31
    const int sslot = tid & 7;      // 16B slot

    for (int k0 = 0; k0 < K; k0 += 64) {
#pragma unroll
        for (int p = 0; p < 4; ++p) {
            int r = p * 32 + srow;
            int gs = sslot ^ (r & 7);
            gload_lds16(Als + (p * 256 + wv * 64) * 16,
                        A + (row0 + r) * K + k0 + gs * 8);
            gload_lds16(Bls + (p * 256 + wv * 64) * 16,
                        Wt + (size_t)(n0 + r) * K + k0 + gs * 8);
        }
        __syncthreads();
#pragma unroll
        for (int kk = 0; kk < 2; ++kk) {
            f16x8 af[4], bf[4];
            const int j = kk * 4 + (lane >> 4);
#pragma unroll
            for (int m = 0; m < 4; ++m) {
                int r = wm * 64 + m * 16 + (lane & 15);
                af[m] = *(const f16x8*)(Als + r * 128 + ((j ^ (r & 7)) * 16));
            }
#pragma unroll
            for (int nn = 0; nn < 4; ++nn) {
                int nr = wn * 64 + nn * 16 + (lane & 15);
                bf[nn] = *(const f16x8*)(Bls + nr * 128 + ((j ^ (nr & 7)) * 16));
            }
#pragma unroll
            for (int m = 0; m < 4; ++m)
#pragma unroll
                for (int nn = 0; nn < 4; ++nn)
                    acc[m][nn] = __builtin_amdgcn_mfma_f32_16x16x32_f16(
                        af[m], bf[nn], acc[m][nn], 0, 0, 0);
        }
        __syncthreads();
    }

    const int cb = lane & 15, rb = lane >> 4;
    const int g0 = POOL ? bsh[0] : 0;
#pragma unroll
    for (int nn = 0; nn < 4; ++nn) {
        const int coll = wn * 64 + nn * 16 + cb;
        const int col = n0 + coll;
        const float bv = bias[col];
        float lsum = 0.f, lsq = 0.f;
#pragma unroll
        for (int m = 0; m < 4; ++m) {
            const int rbase = wm * 64 + m * 16 + rb * 4;
#pragma unroll
            for (int r = 0; r < 4; ++r) {
                const long grow = row0 + rbase + r;
                if (grow < n) {
                    float v = fmaxf(acc[m][nn][r] + bv, 0.f);
                    if constexpr (WRITE_C) C[grow * HDIM + col] = f2h(v);
                    if constexpr (STATS) { lsum += v; lsq += v * v; }
                    if constexpr (POOL) {
                        int seg = bsh[rbase + r] - g0;
                        if (seg < 4) atomicAdd(&psum[seg][coll], v);
                        else atomicAdd(&pooled[(size_t)bsh[rbase + r] * HDIM + col], v);
                    }
                }
            }
        }
        if constexpr (STATS) {
            atomicAdd(&ssum[coll], lsum);
            atomicAdd(&ssq[coll], lsq);
        }
    }
    if constexpr (STATS || POOL) {
        __syncthreads();
        if (tid < 128) {
            if constexpr (STATS) {
                atomicAdd(&stats[n0 + tid], ssum[tid]);
                atomicAdd(&stats[HDIM + n0 + tid], ssq[tid]);
            }
            if constexpr (POOL) {
#pragma unroll
                for (int seg = 0; seg < 4; ++seg) {
                    float v = psum[seg][tid];
                    int g = g0 + seg;
                    if (v != 0.f && g < N_GRAPHS)
                        atomicAdd(&pooled[(size_t)g * HDIM + n0 + tid], v);
                }
            }
        }
    }
}

// -------------------------------------------------------------------- BN
__global__ void k_bn_finalize(const float* __restrict__ stats, const float* __restrict__ g,
                              const float* __restrict__ be, float* __restrict__ st, int n) {
    int f = threadIdx.x;
    float mu = stats[f] / (float)n;
    float var = stats[HDIM + f] / (float)n - mu * mu;
    var = fmaxf(var, 0.f);
    float sc = g[f] * rsqrtf(var + BN_EPS);
    st[f] = sc;
    st[HDIM + f] = be[f] - mu * sc;
}

// ------------------------------------------------------------------ head
// pooled_bn[g][c] = sc[c]*pooled_raw[g][c] + n_g*tb[c]
__global__ __launch_bounds__(256) void k_head(const float* __restrict__ pooled,
                                              const float* __restrict__ st,
                                              const int* __restrict__ gcnt,
                                              const float* __restrict__ w1,
                                              const float* __restrict__ b1,
                                              const float* __restrict__ w2,
                                              const float* __restrict__ b2,
                                              float* __restrict__ out) {
    __shared__ float p[HDIM];
    __shared__ float red[HDIM];
    const int g = blockIdx.x, j = threadIdx.x;
    const float cnt = (float)gcnt[g];
    p[j] = st[j] * pooled[(size_t)g * HDIM + j] + cnt * st[HDIM + j];
    __syncthreads();
    float a = b1[j];
    for (int k = 0; k < HDIM; ++k) a = fmaf(p[k], w1[k * HDIM + j], a);
    a = fmaxf(a, 0.f) * w2[j];
    red[j] = a;
    __syncthreads();
    for (int s = 128; s > 0; s >>= 1) {
        if (j < s) red[j] += red[j + s];
        __syncthreads();
    }
    if (j == 0) out[g] = red[0] + b2[0];
}

// ================================================================= launch
extern "C" void kernel_launch(void* const* d_in, const int* in_sizes, int n_in,
                              void* d_out, int out_size, void* d_ws, size_t ws_size,
                              hipStream_t stream) {
    const float* x     = (const float*)d_in[0];
    const int*   ei    = (const int*)d_in[1];
    const int*   batch = (const int*)d_in[2];
    const float* cw1[3] = {(const float*)d_in[3],  (const float*)d_in[9],  (const float*)d_in[15]};
    const float* cb1[3] = {(const float*)d_in[4],  (const float*)d_in[10], (const float*)d_in[16]};
    const float* cw2[3] = {(const float*)d_in[5],  (const float*)d_in[11], (const float*)d_in[17]};
    const float* cb2[3] = {(const float*)d_in[6],  (const float*)d_in[12], (const float*)d_in[18]};
    const float* cg [3] = {(const float*)d_in[7],  (const float*)d_in[13], (const float*)d_in[19]};
    const float* cbe[3] = {(const float*)d_in[8],  (const float*)d_in[14], (const float*)d_in[20]};
    const float* l1w = (const float*)d_in[21];
    const float* l1b = (const float*)d_in[22];
    const float* l2w = (const float*)d_in[23];
    const float* l2b = (const float*)d_in[24];
    float* out = (float*)d_out;

    const int N = N_NODES, E = N_EDGES;

    uintptr_t base = (uintptr_t)d_ws;
    auto alloc = [&](size_t bytes) {
        uintptr_t p = (base + 255) & ~(uintptr_t)255;
        base = p + bytes;
        return (void*)p;
    };
    unsigned short* xh = (unsigned short*)alloc((size_t)N_NODES * 128 * 2);
    unsigned short* B0 = (unsigned short*)alloc((size_t)NROWS_PAD * HDIM * 2);
    unsigned short* B1 = (unsigned short*)alloc((size_t)NROWS_PAD * HDIM * 2);
    unsigned short* B2 = (unsigned short*)alloc((size_t)NROWS_PAD * HDIM * 2);
    unsigned short* wt[6];
    for (int i = 0; i < 6; ++i) wt[i] = (unsigned short*)alloc((size_t)HDIM * HDIM * 2);
    unsigned* bpack = (unsigned*)alloc((size_t)E * sizeof(unsigned));
    int*   csr_src  = (int*)alloc((size_t)E * sizeof(int));
    int*   bbase    = (int*)alloc((size_t)(NBUCK + 1) * sizeof(int));
    int*   bcur     = (int*)alloc((size_t)NBUCK * sizeof(int));
    int*   row_ptr  = (int*)alloc((size_t)(N + 1) * sizeof(int));
    float* st       = (float*)alloc(2 * HDIM * sizeof(float));

    // ---- zero arena: everything needing zero-init, ONE memset per launch
    uintptr_t zstart = (base + 255) & ~(uintptr_t)255;
    int*   bcnt   = (int*)alloc((size_t)NBUCK * sizeof(int));
    int*   gcnt   = (int*)alloc(N_GRAPHS * sizeof(int));
    float* stats  = (float*)alloc(3 * 2 * HDIM * sizeof(float));   // per-layer slices
    float* pooled = (float*)alloc((size_t)N_GRAPHS * HDIM * sizeof(float));
    size_t zbytes = base - zstart;
    hipMemsetAsync((void*)zstart, 0, zbytes, stream);

    // ---- CSR build (bucketed counting sort)
    const int GB = (E + EPB - 1) / EPB;
    k_bucket_count<<<GB, 256, 0, stream>>>(ei, bcnt, E);
    k_bucket_scan<<<1, 1024, 0, stream>>>(bcnt, bbase, bcur);
    k_bucket_scatter<<<GB, 256, 0, stream>>>(ei, bcur, bpack, E);
    k_bucket_sort<<<NBUCK, 256, 0, stream>>>(bpack, bbase, csr_src, row_ptr, N);

    // ---- weight prep (one dispatch) + x cast + graph counts
    k_cast_x<<<(N * 128 / 4 + 255) / 256, 256, 0, stream>>>(x, xh, N * 128 / 4);
    WArgs wa;
    const float* ws_[6] = {cw1[0], cw2[0], cw1[1], cw2[1], cw1[2], cw2[2]};
    const int    wk_[6] = {128, 256, 256, 256, 256, 256};
    for (int i = 0; i < 6; ++i) { wa.w[i] = ws_[i]; wa.wt[i] = wt[i]; wa.K[i] = wk_[i]; }
    k_prep_w_all<<<dim3(8, 8, 6), 256, 0, stream>>>(wa);
    k_gcnt<<<128, 256, 0, stream>>>(batch, gcnt, N);

    const int agg_grid = (N + 3) / 4;
    const dim3 gemm_grid(NROWS_PAD / 128, 2);

    float* st0 = stats;
    float* st1 = stats + 2 * HDIM;
    float* st2 = stats + 4 * HDIM;

    // ---- layer 1
    k_aggregate_f16<128><<<agg_grid, 256, 0, stream>>>(xh, row_ptr, csr_src, nullptr, B0, N);
    k_gemm_mfma<128, false, false, true><<<gemm_grid, 256, 0, stream>>>(
        B0, wt[0], cb1[0], B1, nullptr, nullptr, nullptr, N);
    k_gemm_mfma<256, true, false, true><<<gemm_grid, 256, 0, stream>>>(
        B1, wt[1], cb2[0], B2, st0, nullptr, nullptr, N);
    k_bn_finalize<<<1, 256, 0, stream>>>(st0, cg[0], cbe[0], st, N);

    // ---- layer 2 (layer-1 BN folded into aggregation)
    k_aggregate_f16<256><<<agg_grid, 256, 0, stream>>>(B2, row_ptr, csr_src, st, B0, N);
    k_gemm_mfma<256, false, false, true><<<gemm_grid, 256, 0, stream>>>(
        B0, wt[2], cb1[1], B1, nullptr, nullptr, nullptr, N);
    k_gemm_mfma<256, true, false, true><<<gemm_grid, 256, 0, stream>>>(
        B1, wt[3], cb2[1], B2, st1, nullptr, nullptr, N);
    k_bn_finalize<<<1, 256, 0, stream>>>(st1, cg[1], cbe[1], st, N);

    // ---- layer 3 (last GEMM: no C-write; fused stats + raw per-graph pool)
    k_aggregate_f16<256><<<agg_grid, 256, 0, stream>>>(B2, row_ptr, csr_src, st, B0, N);
    k_gemm_mfma<256, false, false, true><<<gemm_grid, 256, 0, stream>>>(
        B0, wt[4], cb1[2], B1, nullptr, nullptr, nullptr, N);
    k_gemm_mfma<256, true, true, false><<<gemm_grid, 256, 0, stream>>>(
        B1, wt[5], cb2[2], nullptr, st2, batch, pooled, N);
    k_bn_finalize<<<1, 256, 0, stream>>>(st2, cg[2], cbe[2], st, N);

    // ---- head (applies layer-3 BN to pooled raw sums via gcnt)
    k_head<<<N_GRAPHS, 256, 0, stream>>>(pooled, st, gcnt, l1w, l1b, l2w, l2b, out);
}

// Round 17
// 748.785 us; speedup vs baseline: 1.1122x; 1.1122x over previous
//
#include <hip/hip_runtime.h>
#include <hip/hip_bf16.h>
#include <cstdint>

#define N_NODES   100000
#define N_EDGES   1600000
#define N_GRAPHS  128
#define HDIM      256
#define BN_EPS    1e-5f
#define NROWS_PAD 100096       // 782*128
#define NBUCK     782          // ceil(N/128)
#define EPB       8192         // edges per block, bucket passes
#define CAP       3584         // max edges per bucket

typedef _Float16 f16;
typedef __attribute__((ext_vector_type(8))) _Float16 f16x8;
typedef __attribute__((ext_vector_type(4))) float f32x4;

static __device__ __forceinline__ int imin(int a, int b) { return a < b ? a : b; }
static __device__ __forceinline__ int imax(int a, int b) { return a > b ? a : b; }

static __device__ __forceinline__ float h2f(unsigned short s) {
    return (float)__builtin_bit_cast(f16, s);
}
static __device__ __forceinline__ float hlo(unsigned u) { return h2f((unsigned short)(u & 0xffff)); }
static __device__ __forceinline__ float hhi(unsigned u) { return h2f((unsigned short)(u >> 16)); }
static __device__ __forceinline__ unsigned short f2h(float f) {
    return __builtin_bit_cast(unsigned short, (f16)f);
}
static __device__ __forceinline__ unsigned pk2(float a, float b) {
    return (unsigned)f2h(a) | ((unsigned)f2h(b) << 16);
}

static __device__ __forceinline__ void gload_lds16(void* ldsp, const void* gp) {
    __builtin_amdgcn_global_load_lds(
        (const __attribute__((address_space(1))) void*)gp,
        (__attribute__((address_space(3))) void*)ldsp, 16, 0, 0);
}

// ---------------------------------------------------- CSR build (bucketed)
__global__ __launch_bounds__(256) void k_bucket_count(const int* __restrict__ ei,
                                                      int* __restrict__ bcnt, int E) {
    __shared__ int h[NBUCK];
    for (int i = threadIdx.x; i < NBUCK; i += 256) h[i] = 0;
    __syncthreads();
    const int e0 = blockIdx.x * EPB;
    const int e1 = imin(e0 + EPB, E);
    for (int e = e0 + threadIdx.x; e < e1; e += 256)
        atomicAdd(&h[ei[E + e] >> 7], 1);
    __syncthreads();
    for (int i = threadIdx.x; i < NBUCK; i += 256)
        if (h[i]) atomicAdd(&bcnt[i], h[i]);
}

__global__ __launch_bounds__(1024) void k_bucket_scan(const int* __restrict__ bcnt,
                                                      int* __restrict__ bbase,
                                                      int* __restrict__ bcur) {
    __shared__ int sh[1024];
    const int t = threadIdx.x;
    const int v = (t < NBUCK) ? bcnt[t] : 0;
    sh[t] = v;
    __syncthreads();
    for (int off = 1; off < 1024; off <<= 1) {
        int x = (t >= off) ? sh[t - off] : 0;
        __syncthreads();
        sh[t] += x;
        __syncthreads();
    }
    const int excl = sh[t] - v;
    if (t <= NBUCK) bbase[t] = excl;   // bbase[NBUCK] == E
    if (t < NBUCK)  bcur[t]  = excl;
}

__global__ __launch_bounds__(256) void k_bucket_scatter(const int* __restrict__ ei,
                                                        int* __restrict__ bcur,
                                                        unsigned* __restrict__ bpack, int E) {
    __shared__ int h[NBUCK];
    __shared__ int base[NBUCK];
    for (int i = threadIdx.x; i < NBUCK; i += 256) h[i] = 0;
    __syncthreads();
    const int e0 = blockIdx.x * EPB;
    const int e1 = imin(e0 + EPB, E);
    for (int e = e0 + threadIdx.x; e < e1; e += 256)
        atomicAdd(&h[ei[E + e] >> 7], 1);
    __syncthreads();
    for (int i = threadIdx.x; i < NBUCK; i += 256) {
        int c = h[i];
        base[i] = c ? atomicAdd(&bcur[i], c) : 0;
        h[i] = 0;                       // reuse as block-local cursor
    }
    __syncthreads();
    for (int e = e0 + threadIdx.x; e < e1; e += 256) {
        int d = ei[E + e];
        int b = d >> 7;
        int p = base[b] + atomicAdd(&h[b], 1);
        bpack[p] = ((unsigned)(d & 127) << 17) | (unsigned)ei[e];
    }
}

__global__ __launch_bounds__(256) void k_bucket_sort(const unsigned* __restrict__ bpack,
                                                     const int* __restrict__ bbase,
                                                     int* __restrict__ csr_src,
                                                     int* __restrict__ row_ptr, int n) {
    __shared__ unsigned arr[CAP];
    __shared__ int sorted[CAP];
    __shared__ int hist[128], cur[128];
    const int b = blockIdx.x;
    const int t = threadIdx.x;
    const int lo = bbase[b];
    const int m = imin(bbase[b + 1] - lo, CAP);
    if (t < 128) hist[t] = 0;
    __syncthreads();
    for (int j = t; j < m; j += 256) {
        unsigned p = bpack[lo + j];
        arr[j] = p;
        atomicAdd(&hist[p >> 17], 1);
    }
    __syncthreads();
    if (t < 128) cur[t] = hist[t];
    __syncthreads();
    for (int off = 1; off < 128; off <<= 1) {
        int x = 0;
        if (t < 128 && t >= off) x = cur[t - off];
        __syncthreads();
        if (t < 128) cur[t] += x;
        __syncthreads();
    }
    if (t < 128) {
        int excl = cur[t] - hist[t];
        int node = b * 128 + t;
        if (node < n) row_ptr[node] = lo + excl;
        cur[t] = excl;
    }
    if (b == NBUCK - 1 && t == 0) row_ptr[n] = bbase[NBUCK];
    __syncthreads();
    for (int j = t; j < m; j += 256) {
        unsigned p = arr[j];
        int pos = atomicAdd(&cur[p >> 17], 1);
        sorted[pos] = (int)(p & 0x1ffff);
    }
    __syncthreads();
    for (int j = t; j < m; j += 256) csr_src[lo + j] = sorted[j];
}

// ---------------------------------------------------------------- casts/prep
__global__ void k_cast_x(const float* __restrict__ x, unsigned short* __restrict__ xh, int total4) {
    int i = blockIdx.x * blockDim.x + threadIdx.x;
    if (i < total4) {
        float4 v = reinterpret_cast<const float4*>(x)[i];
        uint2 o;
        o.x = pk2(v.x, v.y);
        o.y = pk2(v.z, v.w);
        reinterpret_cast<uint2*>(xh)[i] = o;
    }
}

// all 6 weights in one dispatch: W[K][256] fp32 -> Wt[256][K] f16
struct WArgs {
    const float* w[6];
    unsigned short* wt[6];
    int K[6];
};

__global__ __launch_bounds__(256) void k_prep_w_all(WArgs a) {
    __shared__ float t[32][33];
    const int i = blockIdx.z;
    const int K = a.K[i];
    const int kb = blockIdx.x * 32;
    if (kb >= K) return;
    const int nb = blockIdx.y * 32;
    const float* w = a.w[i];
    unsigned short* wt = a.wt[i];
    int c = threadIdx.x & 31, r0 = threadIdx.x >> 5;
    for (int r = r0; r < 32; r += 8) t[r][c] = w[(size_t)(kb + r) * HDIM + nb + c];
    __syncthreads();
    for (int r = r0; r < 32; r += 8) wt[(size_t)(nb + r) * K + kb + c] = f2h(t[c][r]);
}

// ------------------------------------------------------------ aggregation
// z = mean_j h_j + h_i, optionally with previous-layer BN folded:
//   z = sc*(mean + self) + tb*(deg>0 ? 2 : 1)
// 16B/lane gather; EPI edges per wave issue; shfl-xor cross-group reduce.
// r17: main loop widened to 16 edges/batch (8 gathers in flight at D=256)
// for memory-level parallelism — agg was at 62% of achievable BW, issue-bound.
template <int D>
__global__ __launch_bounds__(256) void k_aggregate_f16(const unsigned short* __restrict__ h,
                                                       const int* __restrict__ row_ptr,
                                                       const int* __restrict__ csr_src,
                                                       const float* __restrict__ st,
                                                       unsigned short* __restrict__ z, int n) {
    int wid = blockIdx.x * 4 + (threadIdx.x >> 6);
    wid = __builtin_amdgcn_readfirstlane(wid);
    if (wid >= n) return;
    const int lane = threadIdx.x & 63;
    constexpr int LG  = D / 8;       // lanes per row (32 for D=256, 16 for D=128)
    constexpr int EPI = 64 / LG;     // edges per issue (2 or 4)
    const int sub = lane / LG;
    const int col = (lane % LG) * 8;
    const unsigned short* hc = h + col;
    const int beg = row_ptr[wid];
    const int end = row_ptr[wid + 1];

    float acc[8];
#pragma unroll
    for (int j = 0; j < 8; ++j) acc[j] = 0.f;

    auto addv = [&](uint4 v) {
        acc[0] += hlo(v.x); acc[1] += hhi(v.x);
        acc[2] += hlo(v.y); acc[3] += hhi(v.y);
        acc[4] += hlo(v.z); acc[5] += hhi(v.z);
        acc[6] += hlo(v.w); acc[7] += hhi(v.w);
    };

    int e = beg;
    // 16-edge batches: load all indices first, then issue all gathers
    for (; e + 16 <= end; e += 16) {
        int s[16 / EPI];
#pragma unroll
        for (int u = 0; u < 16 / EPI; ++u) s[u] = csr_src[e + u * EPI + sub];
#pragma unroll
        for (int u = 0; u < 16 / EPI; ++u)
            addv(*reinterpret_cast<const uint4*>(hc + (size_t)s[u] * D));
    }
    for (; e + 8 <= end; e += 8) {
        int s[8 / EPI];
#pragma unroll
        for (int u = 0; u < 8 / EPI; ++u) s[u] = csr_src[e + u * EPI + sub];
#pragma unroll
        for (int u = 0; u < 8 / EPI; ++u)
            addv(*reinterpret_cast<const uint4*>(hc + (size_t)s[u] * D));
    }
    for (; e + EPI <= end; e += EPI) {
        int s = csr_src[e + sub];
        addv(*reinterpret_cast<const uint4*>(hc + (size_t)s * D));
    }
    if (e < end && sub < end - e) {
        int s = csr_src[e + sub];
        addv(*reinterpret_cast<const uint4*>(hc + (size_t)s * D));
    }

#pragma unroll
    for (int j = 0; j < 8; ++j) {
        if (EPI == 4) acc[j] += __shfl_xor(acc[j], 16, 64);
        acc[j] += __shfl_xor(acc[j], 32, 64);
    }

    const float inv = 1.0f / (float)imax(end - beg, 1);
    uint4 sv = *reinterpret_cast<const uint4*>(hc + (size_t)wid * D);
    float m[8];
    m[0] = acc[0] * inv + hlo(sv.x); m[1] = acc[1] * inv + hhi(sv.x);
    m[2] = acc[2] * inv + hlo(sv.y); m[3] = acc[3] * inv + hhi(sv.y);
    m[4] = acc[4] * inv + hlo(sv.z); m[5] = acc[5] * inv + hhi(sv.z);
    m[6] = acc[6] * inv + hlo(sv.w); m[7] = acc[7] * inv + hhi(sv.w);
    if (st) {
        const float tbm = (end > beg) ? 2.f : 1.f;
#pragma unroll
        for (int j = 0; j < 8; ++j) m[j] = st[col + j] * m[j] + tbm * st[HDIM + col + j];
    }
    if (sub == 0) {
        uint4 o;
        o.x = pk2(m[0], m[1]); o.y = pk2(m[2], m[3]);
        o.z = pk2(m[4], m[5]); o.w = pk2(m[6], m[7]);
        *reinterpret_cast<uint4*>(z + (size_t)wid * D + col) = o;
    }
}

// ------------------------------------------------------------------- GEMM
// r14 PROVEN-FAST STRUCTURE (745us total, ~57us/GEMM): BM=128, BN=128
// (grid.y=2), BK=64, 256 threads = 4 waves (2x2), wave 64x64, mfma
// 16x16x32 f16. BOTH A and Wt staged via global_load_lds with wave-uniform
// LDS dest (p*256+wv*64)*16 and XOR-pre-swizzled per-lane global source;
// swizzled ds_read_b128 on consume. Compiler-managed waitcnt/barriers ONLY.
// LESSONS (permanently closed): POOL/WRITE_C fusion (r7/r16) — the POOL
// instance reproducibly runs 196us vs 57us, mechanism never isolated, and
// its psum epilogue caused r8's post-timing divergence; NOT worth <=25us.
// BN=256 4-wave (r15) -27us. Per-lane LDS dest (r4/r6/r7) 3x slower.
// W-direct-from-global (r8/r13) 213us. min-waves=4 (r5) spills acc.
// Fused STATS (sum/sumsq) is part of the fast config — keep.
template <int K, bool STATS>
__global__ __launch_bounds__(256, 2) void k_gemm_mfma(const unsigned short* __restrict__ A,
                                                      const unsigned short* __restrict__ Wt,
                                                      const float* __restrict__ bias,
                                                      unsigned short* __restrict__ C,
                                                      float* __restrict__ stats, int n) {
    __shared__ unsigned char Als[128 * 64 * 2];   // 16 KB
    __shared__ unsigned char Bls[128 * 64 * 2];   // 16 KB
    __shared__ float ssum[128], ssq[128];

    const int tid = threadIdx.x;
    const int lane = tid & 63;
    const int wv = tid >> 6;              // 0..3
    const int wm = wv >> 1, wn = wv & 1;  // 2 x 2
    const long row0 = (long)blockIdx.x * 128;
    const int n0 = blockIdx.y * 128;

    if constexpr (STATS) {
        if (tid < 128) { ssum[tid] = 0.f; ssq[tid] = 0.f; }
    }

    f32x4 acc[4][4];
#pragma unroll
    for (int m = 0; m < 4; ++m)
#pragma unroll
        for (int nn = 0; nn < 4; ++nn) acc[m][nn] = (f32x4){0.f, 0.f, 0.f, 0.f};

    const int srow = tid >> 3;      // 0..31
    const int sslot = tid & 7;      // 16B slot

    for (int k0 = 0; k0 < K; k0 += 64) {
#pragma unroll
        for (int p = 0; p < 4; ++p) {
            int r = p * 32 + srow;
            int gs = sslot ^ (r & 7);
            gload_lds16(Als + (p * 256 + wv * 64) * 16,
                        A + (row0 + r) * K + k0 + gs * 8);
            gload_lds16(Bls + (p * 256 + wv * 64) * 16,
                        Wt + (size_t)(n0 + r) * K + k0 + gs * 8);
        }
        __syncthreads();
#pragma unroll
        for (int kk = 0; kk < 2; ++kk) {
            f16x8 af[4], bf[4];
            const int j = kk * 4 + (lane >> 4);
#pragma unroll
            for (int m = 0; m < 4; ++m) {
                int r = wm * 64 + m * 16 + (lane & 15);
                af[m] = *(const f16x8*)(Als + r * 128 + ((j ^ (r & 7)) * 16));
            }
#pragma unroll
            for (int nn = 0; nn < 4; ++nn) {
                int nr = wn * 64 + nn * 16 + (lane & 15);
                bf[nn] = *(const f16x8*)(Bls + nr * 128 + ((j ^ (nr & 7)) * 16));
            }
#pragma unroll
            for (int m = 0; m < 4; ++m)
#pragma unroll
                for (int nn = 0; nn < 4; ++nn)
                    acc[m][nn] = __builtin_amdgcn_mfma_f32_16x16x32_f16(
                        af[m], bf[nn], acc[m][nn], 0, 0, 0);
        }
        __syncthreads();
    }

    const int cb = lane & 15, rb = lane >> 4;
#pragma unroll
    for (int nn = 0; nn < 4; ++nn) {
        const int coll = wn * 64 + nn * 16 + cb;
        const int col = n0 + coll;
        const float bv = bias[col];
        float lsum = 0.f, lsq = 0.f;
#pragma unroll
        for (int m = 0; m < 4; ++m) {
            long grow = row0 + wm * 64 + m * 16 + rb * 4;
#pragma unroll
            for (int r = 0; r < 4; ++r) {
                if (grow + r < n) {
                    float v = fmaxf(acc[m][nn][r] + bv, 0.f);
                    C[(grow + r) * HDIM + col] = f2h(v);
                    if constexpr (STATS) { lsum += v; lsq += v * v; }
                }
            }
        }
        if constexpr (STATS) {
            atomicAdd(&ssum[coll], lsum);
            atomicAdd(&ssq[coll], lsq);
        }
    }
    if constexpr (STATS) {
        __syncthreads();
        if (tid < 128) {
            atomicAdd(&stats[n0 + tid], ssum[tid]);
            atomicAdd(&stats[HDIM + n0 + tid], ssq[tid]);
        }
    }
}

// -------------------------------------------------------------------- BN
__global__ void k_bn_finalize(const float* __restrict__ stats, const float* __restrict__ g,
                              const float* __restrict__ be, float* __restrict__ st, int n) {
    int f = threadIdx.x;
    float mu = stats[f] / (float)n;
    float var = stats[HDIM + f] / (float)n - mu * mu;
    var = fmaxf(var, 0.f);
    float sc = g[f] * rsqrtf(var + BN_EPS);
    st[f] = sc;
    st[HDIM + f] = be[f] - mu * sc;
}

// --------------------------------------------------------------- pooling
// batch sorted; applies layer-3 BN affine while accumulating per graph.
__global__ __launch_bounds__(128) void k_pool_f16(const unsigned short* __restrict__ h,
                                                  const int* __restrict__ batch,
                                                  const float* __restrict__ st,
                                                  float* __restrict__ pooled, int n) {
    __shared__ int bsh[128];
    const int p = threadIdx.x;          // feature pair 0..127
    const int r0 = blockIdx.x * 128;
    const int cnt = imin(128, n - r0);
    if (cnt <= 0) return;
    if (p < cnt) bsh[p] = batch[r0 + p];
    __syncthreads();
    const float sc0 = st[2 * p], sc1 = st[2 * p + 1];
    const float tb0 = st[HDIM + 2 * p], tb1 = st[HDIM + 2 * p + 1];
    float a0 = 0.f, a1 = 0.f;
    int cur = bsh[0];
    for (int i = 0; i < cnt; ++i) {
        int b = bsh[i];
        if (b != cur) {
            atomicAdd(&pooled[cur * HDIM + 2 * p], a0);
            atomicAdd(&pooled[cur * HDIM + 2 * p + 1], a1);
            a0 = a1 = 0.f;
            cur = b;
        }
        unsigned u = *reinterpret_cast<const unsigned*>(h + (size_t)(r0 + i) * HDIM + 2 * p);
        a0 += fmaf(sc0, hlo(u), tb0);
        a1 += fmaf(sc1, hhi(u), tb1);
    }
    atomicAdd(&pooled[cur * HDIM + 2 * p], a0);
    atomicAdd(&pooled[cur * HDIM + 2 * p + 1], a1);
}

// ------------------------------------------------------------------ head
__global__ __launch_bounds__(256) void k_head(const float* __restrict__ pooled,
                                              const float* __restrict__ w1,
                                              const float* __restrict__ b1,
                                              const float* __restrict__ w2,
                                              const float* __restrict__ b2,
                                              float* __restrict__ out) {
    __shared__ float p[HDIM];
    __shared__ float red[HDIM];
    const int g = blockIdx.x, j = threadIdx.x;
    p[j] = pooled[g * HDIM + j];
    __syncthreads();
    float a = b1[j];
    for (int k = 0; k < HDIM; ++k) a = fmaf(p[k], w1[k * HDIM + j], a);
    a = fmaxf(a, 0.f) * w2[j];
    red[j] = a;
    __syncthreads();
    for (int s = 128; s > 0; s >>= 1) {
        if (j < s) red[j] += red[j + s];
        __syncthreads();
    }
    if (j == 0) out[g] = red[0] + b2[0];
}

// ================================================================= launch
extern "C" void kernel_launch(void* const* d_in, const int* in_sizes, int n_in,
                              void* d_out, int out_size, void* d_ws, size_t ws_size,
                              hipStream_t stream) {
    const float* x     = (const float*)d_in[0];
    const int*   ei    = (const int*)d_in[1];
    const int*   batch = (const int*)d_in[2];
    const float* cw1[3] = {(const float*)d_in[3],  (const float*)d_in[9],  (const float*)d_in[15]};
    const float* cb1[3] = {(const float*)d_in[4],  (const float*)d_in[10], (const float*)d_in[16]};
    const float* cw2[3] = {(const float*)d_in[5],  (const float*)d_in[11], (const float*)d_in[17]};
    const float* cb2[3] = {(const float*)d_in[6],  (const float*)d_in[12], (const float*)d_in[18]};
    const float* cg [3] = {(const float*)d_in[7],  (const float*)d_in[13], (const float*)d_in[19]};
    const float* cbe[3] = {(const float*)d_in[8],  (const float*)d_in[14], (const float*)d_in[20]};
    const float* l1w = (const float*)d_in[21];
    const float* l1b = (const float*)d_in[22];
    const float* l2w = (const float*)d_in[23];
    const float* l2b = (const float*)d_in[24];
    float* out = (float*)d_out;

    const int N = N_NODES, E = N_EDGES;

    uintptr_t base = (uintptr_t)d_ws;
    auto alloc = [&](size_t bytes) {
        uintptr_t p = (base + 255) & ~(uintptr_t)255;
        base = p + bytes;
        return (void*)p;
    };
    unsigned short* xh = (unsigned short*)alloc((size_t)N_NODES * 128 * 2);
    unsigned short* B0 = (unsigned short*)alloc((size_t)NROWS_PAD * HDIM * 2);
    unsigned short* B1 = (unsigned short*)alloc((size_t)NROWS_PAD * HDIM * 2);
    unsigned short* B2 = (unsigned short*)alloc((size_t)NROWS_PAD * HDIM * 2);
    unsigned short* wt[6];
    for (int i = 0; i < 6; ++i) wt[i] = (unsigned short*)alloc((size_t)HDIM * HDIM * 2);
    unsigned* bpack = (unsigned*)alloc((size_t)E * sizeof(unsigned));
    int*   csr_src  = (int*)alloc((size_t)E * sizeof(int));
    int*   bbase    = (int*)alloc((size_t)(NBUCK + 1) * sizeof(int));
    int*   bcur     = (int*)alloc((size_t)NBUCK * sizeof(int));
    int*   row_ptr  = (int*)alloc((size_t)(N + 1) * sizeof(int));
    float* st       = (float*)alloc(2 * HDIM * sizeof(float));

    // ---- zero arena: everything needing zero-init, ONE memset per launch
    uintptr_t zstart = (base + 255) & ~(uintptr_t)255;
    int*   bcnt   = (int*)alloc((size_t)NBUCK * sizeof(int));
    float* stats  = (float*)alloc(3 * 2 * HDIM * sizeof(float));   // per-layer slices
    float* pooled = (float*)alloc((size_t)N_GRAPHS * HDIM * sizeof(float));
    size_t zbytes = base - zstart;
    hipMemsetAsync((void*)zstart, 0, zbytes, stream);

    // ---- CSR build (bucketed counting sort)
    const int GB = (E + EPB - 1) / EPB;
    k_bucket_count<<<GB, 256, 0, stream>>>(ei, bcnt, E);
    k_bucket_scan<<<1, 1024, 0, stream>>>(bcnt, bbase, bcur);
    k_bucket_scatter<<<GB, 256, 0, stream>>>(ei, bcur, bpack, E);
    k_bucket_sort<<<NBUCK, 256, 0, stream>>>(bpack, bbase, csr_src, row_ptr, N);

    // ---- weight prep (one dispatch) + x cast
    k_cast_x<<<(N * 128 / 4 + 255) / 256, 256, 0, stream>>>(x, xh, N * 128 / 4);
    WArgs wa;
    const float* ws_[6] = {cw1[0], cw2[0], cw1[1], cw2[1], cw1[2], cw2[2]};
    const int    wk_[6] = {128, 256, 256, 256, 256, 256};
    for (int i = 0; i < 6; ++i) { wa.w[i] = ws_[i]; wa.wt[i] = wt[i]; wa.K[i] = wk_[i]; }
    k_prep_w_all<<<dim3(8, 8, 6), 256, 0, stream>>>(wa);

    const int agg_grid = (N + 3) / 4;
    const dim3 gemm_grid(NROWS_PAD / 128, 2);

    float* st0 = stats;
    float* st1 = stats + 2 * HDIM;
    float* st2 = stats + 4 * HDIM;

    // ---- layer 1
    k_aggregate_f16<128><<<agg_grid, 256, 0, stream>>>(xh, row_ptr, csr_src, nullptr, B0, N);
    k_gemm_mfma<128, false><<<gemm_grid, 256, 0, stream>>>(B0, wt[0], cb1[0], B1, nullptr, N);
    k_gemm_mfma<256, true><<<gemm_grid, 256, 0, stream>>>(B1, wt[1], cb2[0], B2, st0, N);
    k_bn_finalize<<<1, 256, 0, stream>>>(st0, cg[0], cbe[0], st, N);

    // ---- layer 2 (layer-1 BN folded into aggregation)
    k_aggregate_f16<256><<<agg_grid, 256, 0, stream>>>(B2, row_ptr, csr_src, st, B0, N);
    k_gemm_mfma<256, false><<<gemm_grid, 256, 0, stream>>>(B0, wt[2], cb1[1], B1, nullptr, N);
    k_gemm_mfma<256, true><<<gemm_grid, 256, 0, stream>>>(B1, wt[3], cb2[1], B2, st1, N);
    k_bn_finalize<<<1, 256, 0, stream>>>(st1, cg[1], cbe[1], st, N);

    // ---- layer 3
    k_aggregate_f16<256><<<agg_grid, 256, 0, stream>>>(B2, row_ptr, csr_src, st, B0, N);
    k_gemm_mfma<256, false><<<gemm_grid, 256, 0, stream>>>(B0, wt[4], cb1[2], B1, nullptr, N);
    k_gemm_mfma<256, true><<<gemm_grid, 256, 0, stream>>>(B1, wt[5], cb2[2], B0, st2, N);
    k_bn_finalize<<<1, 256, 0, stream>>>(st2, cg[2], cbe[2], st, N);

    // ---- pool (applies layer-3 BN) + head
    k_pool_f16<<<(N + 127) / 128, 128, 0, stream>>>(B0, batch, st, pooled, N);
    k_head<<<N_GRAPHS, 256, 0, stream>>>(pooled, l1w, l1b, l2w, l2b, out);
}

// Round 18
// 730.404 us; speedup vs baseline: 1.1402x; 1.0252x over previous
//
#include <hip/hip_runtime.h>
#include <hip/hip_bf16.h>
#include <cstdint>

#define N_NODES   100000
#define N_EDGES   1600000
#define N_GRAPHS  128
#define HDIM      256
#define BN_EPS    1e-5f
#define NROWS_PAD 100096       // 782*128
#define NBUCK     782          // ceil(N/128)
#define EPB       8192         // edges per block, bucket passes
#define CAP       3584         // max edges per bucket

typedef _Float16 f16;
typedef __attribute__((ext_vector_type(8))) _Float16 f16x8;
typedef __attribute__((ext_vector_type(4))) float f32x4;

static __device__ __forceinline__ int imin(int a, int b) { return a < b ? a : b; }
static __device__ __forceinline__ int imax(int a, int b) { return a > b ? a : b; }

static __device__ __forceinline__ float h2f(unsigned short s) {
    return (float)__builtin_bit_cast(f16, s);
}
static __device__ __forceinline__ float hlo(unsigned u) { return h2f((unsigned short)(u & 0xffff)); }
static __device__ __forceinline__ float hhi(unsigned u) { return h2f((unsigned short)(u >> 16)); }
static __device__ __forceinline__ unsigned short f2h(float f) {
    return __builtin_bit_cast(unsigned short, (f16)f);
}
static __device__ __forceinline__ unsigned pk2(float a, float b) {
    return (unsigned)f2h(a) | ((unsigned)f2h(b) << 16);
}

static __device__ __forceinline__ void gload_lds16(void* ldsp, const void* gp) {
    __builtin_amdgcn_global_load_lds(
        (const __attribute__((address_space(1))) void*)gp,
        (__attribute__((address_space(3))) void*)ldsp, 16, 0, 0);
}

// ---------------------------------------------------- CSR build (bucketed)
__global__ __launch_bounds__(256) void k_bucket_count(const int* __restrict__ ei,
                                                      int* __restrict__ bcnt, int E) {
    __shared__ int h[NBUCK];
    for (int i = threadIdx.x; i < NBUCK; i += 256) h[i] = 0;
    __syncthreads();
    const int e0 = blockIdx.x * EPB;
    const int e1 = imin(e0 + EPB, E);
    for (int e = e0 + threadIdx.x; e < e1; e += 256)
        atomicAdd(&h[ei[E + e] >> 7], 1);
    __syncthreads();
    for (int i = threadIdx.x; i < NBUCK; i += 256)
        if (h[i]) atomicAdd(&bcnt[i], h[i]);
}

__global__ __launch_bounds__(1024) void k_bucket_scan(const int* __restrict__ bcnt,
                                                      int* __restrict__ bbase,
                                                      int* __restrict__ bcur) {
    __shared__ int sh[1024];
    const int t = threadIdx.x;
    const int v = (t < NBUCK) ? bcnt[t] : 0;
    sh[t] = v;
    __syncthreads();
    for (int off = 1; off < 1024; off <<= 1) {
        int x = (t >= off) ? sh[t - off] : 0;
        __syncthreads();
        sh[t] += x;
        __syncthreads();
    }
    const int excl = sh[t] - v;
    if (t <= NBUCK) bbase[t] = excl;   // bbase[NBUCK] == E
    if (t < NBUCK)  bcur[t]  = excl;
}

__global__ __launch_bounds__(256) void k_bucket_scatter(const int* __restrict__ ei,
                                                        int* __restrict__ bcur,
                                                        unsigned* __restrict__ bpack, int E) {
    __shared__ int h[NBUCK];
    __shared__ int base[NBUCK];
    for (int i = threadIdx.x; i < NBUCK; i += 256) h[i] = 0;
    __syncthreads();
    const int e0 = blockIdx.x * EPB;
    const int e1 = imin(e0 + EPB, E);
    for (int e = e0 + threadIdx.x; e < e1; e += 256)
        atomicAdd(&h[ei[E + e] >> 7], 1);
    __syncthreads();
    for (int i = threadIdx.x; i < NBUCK; i += 256) {
        int c = h[i];
        base[i] = c ? atomicAdd(&bcur[i], c) : 0;
        h[i] = 0;                       // reuse as block-local cursor
    }
    __syncthreads();
    for (int e = e0 + threadIdx.x; e < e1; e += 256) {
        int d = ei[E + e];
        int b = d >> 7;
        int p = base[b] + atomicAdd(&h[b], 1);
        bpack[p] = ((unsigned)(d & 127) << 17) | (unsigned)ei[e];
    }
}

__global__ __launch_bounds__(256) void k_bucket_sort(const unsigned* __restrict__ bpack,
                                                     const int* __restrict__ bbase,
                                                     int* __restrict__ csr_src,
                                                     int* __restrict__ row_ptr, int n) {
    __shared__ unsigned arr[CAP];
    __shared__ int sorted[CAP];
    __shared__ int hist[128], cur[128];
    const int b = blockIdx.x;
    const int t = threadIdx.x;
    const int lo = bbase[b];
    const int m = imin(bbase[b + 1] - lo, CAP);
    if (t < 128) hist[t] = 0;
    __syncthreads();
    for (int j = t; j < m; j += 256) {
        unsigned p = bpack[lo + j];
        arr[j] = p;
        atomicAdd(&hist[p >> 17], 1);
    }
    __syncthreads();
    if (t < 128) cur[t] = hist[t];
    __syncthreads();
    for (int off = 1; off < 128; off <<= 1) {
        int x = 0;
        if (t < 128 && t >= off) x = cur[t - off];
        __syncthreads();
        if (t < 128) cur[t] += x;
        __syncthreads();
    }
    if (t < 128) {
        int excl = cur[t] - hist[t];
        int node = b * 128 + t;
        if (node < n) row_ptr[node] = lo + excl;
        cur[t] = excl;
    }
    if (b == NBUCK - 1 && t == 0) row_ptr[n] = bbase[NBUCK];
    __syncthreads();
    for (int j = t; j < m; j += 256) {
        unsigned p = arr[j];
        int pos = atomicAdd(&cur[p >> 17], 1);
        sorted[pos] = (int)(p & 0x1ffff);
    }
    __syncthreads();
    for (int j = t; j < m; j += 256) csr_src[lo + j] = sorted[j];
}

// ---------------------------------------------------------------- casts/prep
__global__ void k_cast_x(const float* __restrict__ x, unsigned short* __restrict__ xh, int total4) {
    int i = blockIdx.x * blockDim.x + threadIdx.x;
    if (i < total4) {
        float4 v = reinterpret_cast<const float4*>(x)[i];
        uint2 o;
        o.x = pk2(v.x, v.y);
        o.y = pk2(v.z, v.w);
        reinterpret_cast<uint2*>(xh)[i] = o;
    }
}

// all 6 weights in one dispatch: W[K][256] fp32 -> Wt[256][K] f16
struct WArgs {
    const float* w[6];
    unsigned short* wt[6];
    int K[6];
};

__global__ __launch_bounds__(256) void k_prep_w_all(WArgs a) {
    __shared__ float t[32][33];
    const int i = blockIdx.z;
    const int K = a.K[i];
    const int kb = blockIdx.x * 32;
    if (kb >= K) return;
    const int nb = blockIdx.y * 32;
    const float* w = a.w[i];
    unsigned short* wt = a.wt[i];
    int c = threadIdx.x & 31, r0 = threadIdx.x >> 5;
    for (int r = r0; r < 32; r += 8) t[r][c] = w[(size_t)(kb + r) * HDIM + nb + c];
    __syncthreads();
    for (int r = r0; r < 32; r += 8) wt[(size_t)(nb + r) * K + kb + c] = f2h(t[c][r]);
}

// ------------------------------------------------------------ aggregation
// z = mean_j h_j + h_i, optionally with previous-layer BN folded:
//   z = sc*(mean + self) + tb*(deg>0 ? 2 : 1)
// 16B/lane gather; EPI edges per wave issue; shfl-xor cross-group reduce.
// CLOSED (r17 probe): 16-edge batching is NULL — same 118us/3.9TB/s at
// 56% occupancy. Aggregation is at its bandwidth plateau (~7.8TB/s
// effective mixed L2/L3), not issue-limited. Keep the 8-edge form (VGPR 24,
// 75% occupancy).
template <int D>
__global__ __launch_bounds__(256) void k_aggregate_f16(const unsigned short* __restrict__ h,
                                                       const int* __restrict__ row_ptr,
                                                       const int* __restrict__ csr_src,
                                                       const float* __restrict__ st,
                                                       unsigned short* __restrict__ z, int n) {
    int wid = blockIdx.x * 4 + (threadIdx.x >> 6);
    wid = __builtin_amdgcn_readfirstlane(wid);
    if (wid >= n) return;
    const int lane = threadIdx.x & 63;
    constexpr int LG  = D / 8;       // lanes per row (32 for D=256, 16 for D=128)
    constexpr int EPI = 64 / LG;     // edges per issue (2 or 4)
    const int sub = lane / LG;
    const int col = (lane % LG) * 8;
    const unsigned short* hc = h + col;
    const int beg = row_ptr[wid];
    const int end = row_ptr[wid + 1];

    float acc[8];
#pragma unroll
    for (int j = 0; j < 8; ++j) acc[j] = 0.f;

    auto addv = [&](uint4 v) {
        acc[0] += hlo(v.x); acc[1] += hhi(v.x);
        acc[2] += hlo(v.y); acc[3] += hhi(v.y);
        acc[4] += hlo(v.z); acc[5] += hhi(v.z);
        acc[6] += hlo(v.w); acc[7] += hhi(v.w);
    };

    int e = beg;
    for (; e + 8 <= end; e += 8) {
        int s[8 / EPI];
#pragma unroll
        for (int u = 0; u < 8 / EPI; ++u) s[u] = csr_src[e + u * EPI + sub];
#pragma unroll
        for (int u = 0; u < 8 / EPI; ++u)
            addv(*reinterpret_cast<const uint4*>(hc + (size_t)s[u] * D));
    }
    for (; e + EPI <= end; e += EPI) {
        int s = csr_src[e + sub];
        addv(*reinterpret_cast<const uint4*>(hc + (size_t)s * D));
    }
    if (e < end && sub < end - e) {
        int s = csr_src[e + sub];
        addv(*reinterpret_cast<const uint4*>(hc + (size_t)s * D));
    }

#pragma unroll
    for (int j = 0; j < 8; ++j) {
        if (EPI == 4) acc[j] += __shfl_xor(acc[j], 16, 64);
        acc[j] += __shfl_xor(acc[j], 32, 64);
    }

    const float inv = 1.0f / (float)imax(end - beg, 1);
    uint4 sv = *reinterpret_cast<const uint4*>(hc + (size_t)wid * D);
    float m[8];
    m[0] = acc[0] * inv + hlo(sv.x); m[1] = acc[1] * inv + hhi(sv.x);
    m[2] = acc[2] * inv + hlo(sv.y); m[3] = acc[3] * inv + hhi(sv.y);
    m[4] = acc[4] * inv + hlo(sv.z); m[5] = acc[5] * inv + hhi(sv.z);
    m[6] = acc[6] * inv + hlo(sv.w); m[7] = acc[7] * inv + hhi(sv.w);
    if (st) {
        const float tbm = (end > beg) ? 2.f : 1.f;
#pragma unroll
        for (int j = 0; j < 8; ++j) m[j] = st[col + j] * m[j] + tbm * st[HDIM + col + j];
    }
    if (sub == 0) {
        uint4 o;
        o.x = pk2(m[0], m[1]); o.y = pk2(m[2], m[3]);
        o.z = pk2(m[4], m[5]); o.w = pk2(m[6], m[7]);
        *reinterpret_cast<uint4*>(z + (size_t)wid * D + col) = o;
    }
}

// ------------------------------------------------------------------- GEMM
// r14 PROVEN-FAST STRUCTURE (745us total, ~57us/GEMM): BM=128, BN=128
// (grid.y=2), BK=64, 256 threads = 4 waves (2x2), wave 64x64, mfma
// 16x16x32 f16. BOTH A and Wt staged via global_load_lds with wave-uniform
// LDS dest (p*256+wv*64)*16 and XOR-pre-swizzled per-lane global source;
// swizzled ds_read_b128 on consume. Compiler-managed waitcnt/barriers ONLY.
// LESSONS (permanently closed): POOL/WRITE_C fusion (r7/r16) 196us +
// r8 divergence; BN=256 4-wave (r15) -27us; per-lane LDS dest (r4/r6/r7)
// 3x slower; W-direct-from-global (r8/r13) 213us; min-waves=4 (r5) spills.
// Fused STATS (sum/sumsq) is part of the fast config — keep.
template <int K, bool STATS>
__global__ __launch_bounds__(256, 2) void k_gemm_mfma(const unsigned short* __restrict__ A,
                                                      const unsigned short* __restrict__ Wt,
                                                      const float* __restrict__ bias,
                                                      unsigned short* __restrict__ C,
                                                      float* __restrict__ stats, int n) {
    __shared__ unsigned char Als[128 * 64 * 2];   // 16 KB
    __shared__ unsigned char Bls[128 * 64 * 2];   // 16 KB
    __shared__ float ssum[128], ssq[128];

    const int tid = threadIdx.x;
    const int lane = tid & 63;
    const int wv = tid >> 6;              // 0..3
    const int wm = wv >> 1, wn = wv & 1;  // 2 x 2
    const long row0 = (long)blockIdx.x * 128;
    const int n0 = blockIdx.y * 128;

    if constexpr (STATS) {
        if (tid < 128) { ssum[tid] = 0.f; ssq[tid] = 0.f; }
    }

    f32x4 acc[4][4];
#pragma unroll
    for (int m = 0; m < 4; ++m)
#pragma unroll
        for (int nn = 0; nn < 4; ++nn) acc[m][nn] = (f32x4){0.f, 0.f, 0.f, 0.f};

    const int srow = tid >> 3;      // 0..31
    const int sslot = tid & 7;      // 16B slot

    for (int k0 = 0; k0 < K; k0 += 64) {
#pragma unroll
        for (int p = 0; p < 4; ++p) {
            int r = p * 32 + srow;
            int gs = sslot ^ (r & 7);
            gload_lds16(Als + (p * 256 + wv * 64) * 16,
                        A + (row0 + r) * K + k0 + gs * 8);
            gload_lds16(Bls + (p * 256 + wv * 64) * 16,
                        Wt + (size_t)(n0 + r) * K + k0 + gs * 8);
        }
        __syncthreads();
#pragma unroll
        for (int kk = 0; kk < 2; ++kk) {
            f16x8 af[4], bf[4];
            const int j = kk * 4 + (lane >> 4);
#pragma unroll
            for (int m = 0; m < 4; ++m) {
                int r = wm * 64 + m * 16 + (lane & 15);
                af[m] = *(const f16x8*)(Als + r * 128 + ((j ^ (r & 7)) * 16));
            }
#pragma unroll
            for (int nn = 0; nn < 4; ++nn) {
                int nr = wn * 64 + nn * 16 + (lane & 15);
                bf[nn] = *(const f16x8*)(Bls + nr * 128 + ((j ^ (nr & 7)) * 16));
            }
#pragma unroll
            for (int m = 0; m < 4; ++m)
#pragma unroll
                for (int nn = 0; nn < 4; ++nn)
                    acc[m][nn] = __builtin_amdgcn_mfma_f32_16x16x32_f16(
                        af[m], bf[nn], acc[m][nn], 0, 0, 0);
        }
        __syncthreads();
    }

    const int cb = lane & 15, rb = lane >> 4;
#pragma unroll
    for (int nn = 0; nn < 4; ++nn) {
        const int coll = wn * 64 + nn * 16 + cb;
        const int col = n0 + coll;
        const float bv = bias[col];
        float lsum = 0.f, lsq = 0.f;
#pragma unroll
        for (int m = 0; m < 4; ++m) {
            long grow = row0 + wm * 64 + m * 16 + rb * 4;
#pragma unroll
            for (int r = 0; r < 4; ++r) {
                if (grow + r < n) {
                    float v = fmaxf(acc[m][nn][r] + bv, 0.f);
                    C[(grow + r) * HDIM + col] = f2h(v);
                    if constexpr (STATS) { lsum += v; lsq += v * v; }
                }
            }
        }
        if constexpr (STATS) {
            atomicAdd(&ssum[coll], lsum);
            atomicAdd(&ssq[coll], lsq);
        }
    }
    if constexpr (STATS) {
        __syncthreads();
        if (tid < 128) {
            atomicAdd(&stats[n0 + tid], ssum[tid]);
            atomicAdd(&stats[HDIM + n0 + tid], ssq[tid]);
        }
    }
}

// -------------------------------------------------------------------- BN
__global__ void k_bn_finalize(const float* __restrict__ stats, const float* __restrict__ g,
                              const float* __restrict__ be, float* __restrict__ st, int n) {
    int f = threadIdx.x;
    float mu = stats[f] / (float)n;
    float var = stats[HDIM + f] / (float)n - mu * mu;
    var = fmaxf(var, 0.f);
    float sc = g[f] * rsqrtf(var + BN_EPS);
    st[f] = sc;
    st[HDIM + f] = be[f] - mu * sc;
}

// --------------------------------------------------------------- pooling
// batch sorted; applies layer-3 BN affine while accumulating per graph.
__global__ __launch_bounds__(128) void k_pool_f16(const unsigned short* __restrict__ h,
                                                  const int* __restrict__ batch,
                                                  const float* __restrict__ st,
                                                  float* __restrict__ pooled, int n) {
    __shared__ int bsh[128];
    const int p = threadIdx.x;          // feature pair 0..127
    const int r0 = blockIdx.x * 128;
    const int cnt = imin(128, n - r0);
    if (cnt <= 0) return;
    if (p < cnt) bsh[p] = batch[r0 + p];
    __syncthreads();
    const float sc0 = st[2 * p], sc1 = st[2 * p + 1];
    const float tb0 = st[HDIM + 2 * p], tb1 = st[HDIM + 2 * p + 1];
    float a0 = 0.f, a1 = 0.f;
    int cur = bsh[0];
    for (int i = 0; i < cnt; ++i) {
        int b = bsh[i];
        if (b != cur) {
            atomicAdd(&pooled[cur * HDIM + 2 * p], a0);
            atomicAdd(&pooled[cur * HDIM + 2 * p + 1], a1);
            a0 = a1 = 0.f;
            cur = b;
        }
        unsigned u = *reinterpret_cast<const unsigned*>(h + (size_t)(r0 + i) * HDIM + 2 * p);
        a0 += fmaf(sc0, hlo(u), tb0);
        a1 += fmaf(sc1, hhi(u), tb1);
    }
    atomicAdd(&pooled[cur * HDIM + 2 * p], a0);
    atomicAdd(&pooled[cur * HDIM + 2 * p + 1], a1);
}

// ------------------------------------------------------------------ head
__global__ __launch_bounds__(256) void k_head(const float* __restrict__ pooled,
                                              const float* __restrict__ w1,
                                              const float* __restrict__ b1,
                                              const float* __restrict__ w2,
                                              const float* __restrict__ b2,
                                              float* __restrict__ out) {
    __shared__ float p[HDIM];
    __shared__ float red[HDIM];
    const int g = blockIdx.x, j = threadIdx.x;
    p[j] = pooled[g * HDIM + j];
    __syncthreads();
    float a = b1[j];
    for (int k = 0; k < HDIM; ++k) a = fmaf(p[k], w1[k * HDIM + j], a);
    a = fmaxf(a, 0.f) * w2[j];
    red[j] = a;
    __syncthreads();
    for (int s = 128; s > 0; s >>= 1) {
        if (j < s) red[j] += red[j + s];
        __syncthreads();
    }
    if (j == 0) out[g] = red[0] + b2[0];
}

// ================================================================= launch
extern "C" void kernel_launch(void* const* d_in, const int* in_sizes, int n_in,
                              void* d_out, int out_size, void* d_ws, size_t ws_size,
                              hipStream_t stream) {
    const float* x     = (const float*)d_in[0];
    const int*   ei    = (const int*)d_in[1];
    const int*   batch = (const int*)d_in[2];
    const float* cw1[3] = {(const float*)d_in[3],  (const float*)d_in[9],  (const float*)d_in[15]};
    const float* cb1[3] = {(const float*)d_in[4],  (const float*)d_in[10], (const float*)d_in[16]};
    const float* cw2[3] = {(const float*)d_in[5],  (const float*)d_in[11], (const float*)d_in[17]};
    const float* cb2[3] = {(const float*)d_in[6],  (const float*)d_in[12], (const float*)d_in[18]};
    const float* cg [3] = {(const float*)d_in[7],  (const float*)d_in[13], (const float*)d_in[19]};
    const float* cbe[3] = {(const float*)d_in[8],  (const float*)d_in[14], (const float*)d_in[20]};
    const float* l1w = (const float*)d_in[21];
    const float* l1b = (const float*)d_in[22];
    const float* l2w = (const float*)d_in[23];
    const float* l2b = (const float*)d_in[24];
    float* out = (float*)d_out;

    const int N = N_NODES, E = N_EDGES;

    uintptr_t base = (uintptr_t)d_ws;
    auto alloc = [&](size_t bytes) {
        uintptr_t p = (base + 255) & ~(uintptr_t)255;
        base = p + bytes;
        return (void*)p;
    };
    unsigned short* xh = (unsigned short*)alloc((size_t)N_NODES * 128 * 2);
    unsigned short* B0 = (unsigned short*)alloc((size_t)NROWS_PAD * HDIM * 2);
    unsigned short* B1 = (unsigned short*)alloc((size_t)NROWS_PAD * HDIM * 2);
    unsigned short* B2 = (unsigned short*)alloc((size_t)NROWS_PAD * HDIM * 2);
    unsigned short* wt[6];
    for (int i = 0; i < 6; ++i) wt[i] = (unsigned short*)alloc((size_t)HDIM * HDIM * 2);
    unsigned* bpack = (unsigned*)alloc((size_t)E * sizeof(unsigned));
    int*   csr_src  = (int*)alloc((size_t)E * sizeof(int));
    int*   bbase    = (int*)alloc((size_t)(NBUCK + 1) * sizeof(int));
    int*   bcur     = (int*)alloc((size_t)NBUCK * sizeof(int));
    int*   row_ptr  = (int*)alloc((size_t)(N + 1) * sizeof(int));
    float* st       = (float*)alloc(2 * HDIM * sizeof(float));

    // ---- zero arena: everything needing zero-init, ONE memset per launch
    uintptr_t zstart = (base + 255) & ~(uintptr_t)255;
    int*   bcnt   = (int*)alloc((size_t)NBUCK * sizeof(int));
    float* stats  = (float*)alloc(3 * 2 * HDIM * sizeof(float));   // per-layer slices
    float* pooled = (float*)alloc((size_t)N_GRAPHS * HDIM * sizeof(float));
    size_t zbytes = base - zstart;
    hipMemsetAsync((void*)zstart, 0, zbytes, stream);

    // ---- CSR build (bucketed counting sort)
    const int GB = (E + EPB - 1) / EPB;
    k_bucket_count<<<GB, 256, 0, stream>>>(ei, bcnt, E);
    k_bucket_scan<<<1, 1024, 0, stream>>>(bcnt, bbase, bcur);
    k_bucket_scatter<<<GB, 256, 0, stream>>>(ei, bcur, bpack, E);
    k_bucket_sort<<<NBUCK, 256, 0, stream>>>(bpack, bbase, csr_src, row_ptr, N);

    // ---- weight prep (one dispatch) + x cast
    k_cast_x<<<(N * 128 / 4 + 255) / 256, 256, 0, stream>>>(x, xh, N * 128 / 4);
    WArgs wa;
    const float* ws_[6] = {cw1[0], cw2[0], cw1[1], cw2[1], cw1[2], cw2[2]};
    const int    wk_[6] = {128, 256, 256, 256, 256, 256};
    for (int i = 0; i < 6; ++i) { wa.w[i] = ws_[i]; wa.wt[i] = wt[i]; wa.K[i] = wk_[i]; }
    k_prep_w_all<<<dim3(8, 8, 6), 256, 0, stream>>>(wa);

    const int agg_grid = (N + 3) / 4;
    const dim3 gemm_grid(NROWS_PAD / 128, 2);

    float* st0 = stats;
    float* st1 = stats + 2 * HDIM;
    float* st2 = stats + 4 * HDIM;

    // ---- layer 1
    k_aggregate_f16<128><<<agg_grid, 256, 0, stream>>>(xh, row_ptr, csr_src, nullptr, B0, N);
    k_gemm_mfma<128, false><<<gemm_grid, 256, 0, stream>>>(B0, wt[0], cb1[0], B1, nullptr, N);
    k_gemm_mfma<256, true><<<gemm_grid, 256, 0, stream>>>(B1, wt[1], cb2[0], B2, st0, N);
    k_bn_finalize<<<1, 256, 0, stream>>>(st0, cg[0], cbe[0], st, N);

    // ---- layer 2 (layer-1 BN folded into aggregation)
    k_aggregate_f16<256><<<agg_grid, 256, 0, stream>>>(B2, row_ptr, csr_src, st, B0, N);
    k_gemm_mfma<256, false><<<gemm_grid, 256, 0, stream>>>(B0, wt[2], cb1[1], B1, nullptr, N);
    k_gemm_mfma<256, true><<<gemm_grid, 256, 0, stream>>>(B1, wt[3], cb2[1], B2, st1, N);
    k_bn_finalize<<<1, 256, 0, stream>>>(st1, cg[1], cbe[1], st, N);

    // ---- layer 3
    k_aggregate_f16<256><<<agg_grid, 256, 0, stream>>>(B2, row_ptr, csr_src, st, B0, N);
    k_gemm_mfma<256, false><<<gemm_grid, 256, 0, stream>>>(B0, wt[4], cb1[2], B1, nullptr, N);
    k_gemm_mfma<256, true><<<gemm_grid, 256, 0, stream>>>(B1, wt[5], cb2[2], B0, st2, N);
    k_bn_finalize<<<1, 256, 0, stream>>>(st2, cg[2], cbe[2], st, N);

    // ---- pool (applies layer-3 BN) + head
    k_pool_f16<<<(N + 127) / 128, 128, 0, stream>>>(B0, batch, st, pooled, N);
    k_head<<<N_GRAPHS, 256, 0, stream>>>(pooled, l1w, l1b, l2w, l2b, out);
}